// Round 3
// baseline (122.789 us; speedup 1.0000x reference)
//
#include <hip/hip_runtime.h>
#include <math.h>

// Problem constants (fixed by setup_inputs)
constexpr int Bc = 256, Sc = 1024, Dc = 32, Kc = 512;
constexpr int ST = 128;                      // s-rows per main block
constexpr float LOG2E    = 1.4426950408889634f;
constexpr float LN2      = 0.6931471805599453f;
constexpr float LOG_NORM = 29.40603306051f;  // D * 0.5 * log(2*pi)

typedef __attribute__((ext_vector_type(8))) short          bf16x8;
typedef __attribute__((ext_vector_type(8))) unsigned short u16x8;
typedef __attribute__((ext_vector_type(4))) float          f32x4;

#if __has_builtin(__builtin_amdgcn_exp2f)
#define EXP2F(v) __builtin_amdgcn_exp2f(v)
#else
#define EXP2F(v) exp2f(v)
#endif
#if __has_builtin(__builtin_amdgcn_logf)
#define LOG2F(v) __builtin_amdgcn_logf(v)
#else
#define LOG2F(v) log2f(v)
#endif

__device__ __forceinline__ unsigned short f2bf(float f) {
    unsigned u = __float_as_uint(f);
    u += 0x7fff + ((u >> 16) & 1);           // round-to-nearest-even
    return (unsigned short)(u >> 16);
}

// ---------------- pre-kernel: per-(b,k) weights + means->bf16 ----------------
// grid(Bc), block(256). Writes:
//   mbf[k*32+d]  : bf16 means (block b owns rows 2b, 2b+1)
//   wbuf[b*K+k]  : exp2((logit[b,k] - lse(b) - 0.5*||mu_k||^2) * log2e)
__global__ __launch_bounds__(256)
void gm_prep(const float* __restrict__ logits, const float* __restrict__ means,
             float* __restrict__ wbuf, unsigned short* __restrict__ mbf)
{
    __shared__ float red[8];
    const int tid  = threadIdx.x;
    const int lane = tid & 63;
    const int wid  = tid >> 6;
    const int b    = blockIdx.x;

    const float l0 = logits[b * Kc + tid];
    const float l1 = logits[b * Kc + tid + 256];
    float mx = fmaxf(l0, l1);
    #pragma unroll
    for (int off = 32; off >= 1; off >>= 1) mx = fmaxf(mx, __shfl_xor(mx, off));
    if (lane == 0) red[wid] = mx;
    __syncthreads();
    mx = fmaxf(fmaxf(red[0], red[1]), fmaxf(red[2], red[3]));
    float sm = EXP2F((l0 - mx) * LOG2E) + EXP2F((l1 - mx) * LOG2E);
    #pragma unroll
    for (int off = 32; off >= 1; off >>= 1) sm += __shfl_xor(sm, off);
    if (lane == 0) red[4 + wid] = sm;
    __syncthreads();
    sm = red[4] + red[5] + red[6] + red[7];
    const float lse = mx + LN2 * LOG2F(sm);

    #pragma unroll
    for (int rr = 0; rr < 2; ++rr) {
        const int k = tid + rr * 256;
        const float4* mp = (const float4*)(means + (size_t)k * Dc);
        float m2 = 0.f;
        #pragma unroll
        for (int i = 0; i < 8; ++i) {
            float4 v = mp[i];
            m2 += v.x*v.x + v.y*v.y + v.z*v.z + v.w*v.w;
        }
        const float lg = (rr == 0) ? l0 : l1;
        wbuf[(size_t)b * Kc + k] = EXP2F((lg - lse - 0.5f * m2) * LOG2E);
    }

    // means -> bf16 (each block converts its 2 owned rows; 64 threads suffice)
    if (tid < 64) {
        const int row = 2 * b + (tid >> 5);
        const int col = tid & 31;
        mbf[row * 32 + col] = f2bf(means[(size_t)row * 32 + col]);
    }
}

// ---------------- main kernel ----------------
// grid(Bc * Sc/ST), block(256) = 4 waves; wave owns 32 s-rows.
__global__ __launch_bounds__(256)
void gm_main(const float* __restrict__ x, const float* __restrict__ wbuf,
             const unsigned short* __restrict__ mbf, float* __restrict__ out)
{
    __shared__ unsigned short mlds[Kc * 32];  // 32 KB pre-converted bf16 means
    __shared__ float x2p[ST];                 // per-row sum(x^2)

    const int tid  = threadIdx.x;
    const int lane = tid & 63;
    const int wid  = tid >> 6;
    const int b    = blockIdx.x >> 3;
    const int s0   = (blockIdx.x & 7) * ST;
    const int q    = lane >> 4;               // k-octet of contraction dim
    const int ln   = lane & 15;
    const int rw   = wid * 32;

    // stage means: straight 32 KB vector copy (no conversion needed)
    {
        const u16x8* src = (const u16x8*)mbf;
        u16x8*       dst = (u16x8*)mlds;
        #pragma unroll
        for (int j = 0; j < 8; ++j) dst[tid + j * 256] = src[tid + j * 256];
    }

    // x A-fragments loaded directly from global (row fully consumed by 4 q-lanes)
    const int row0 = rw + ln, row1 = row0 + 16;
    const float4* xp0 = (const float4*)(x + ((size_t)b * Sc + s0 + row0) * Dc) + q * 2;
    const float4* xp1 = (const float4*)(x + ((size_t)b * Sc + s0 + row1) * Dc) + q * 2;
    float4 v0 = xp0[0], v1 = xp0[1];
    float4 u0 = xp1[0], u1 = xp1[1];

    bf16x8 a0, a1;
    a0[0]=(short)f2bf(v0.x*LOG2E); a0[1]=(short)f2bf(v0.y*LOG2E);
    a0[2]=(short)f2bf(v0.z*LOG2E); a0[3]=(short)f2bf(v0.w*LOG2E);
    a0[4]=(short)f2bf(v1.x*LOG2E); a0[5]=(short)f2bf(v1.y*LOG2E);
    a0[6]=(short)f2bf(v1.z*LOG2E); a0[7]=(short)f2bf(v1.w*LOG2E);
    a1[0]=(short)f2bf(u0.x*LOG2E); a1[1]=(short)f2bf(u0.y*LOG2E);
    a1[2]=(short)f2bf(u0.z*LOG2E); a1[3]=(short)f2bf(u0.w*LOG2E);
    a1[4]=(short)f2bf(u1.x*LOG2E); a1[5]=(short)f2bf(u1.y*LOG2E);
    a1[6]=(short)f2bf(u1.z*LOG2E); a1[7]=(short)f2bf(u1.w*LOG2E);

    float p0 = v0.x*v0.x + v0.y*v0.y + v0.z*v0.z + v0.w*v0.w
             + v1.x*v1.x + v1.y*v1.y + v1.z*v1.z + v1.w*v1.w;
    float p1 = u0.x*u0.x + u0.y*u0.y + u0.z*u0.z + u0.w*u0.w
             + u1.x*u1.x + u1.y*u1.y + u1.z*u1.z + u1.w*u1.w;
    p0 += __shfl_xor(p0, 16); p0 += __shfl_xor(p0, 32);   // sum over q-groups
    p1 += __shfl_xor(p1, 16); p1 += __shfl_xor(p1, 32);
    if (q == 0) { x2p[row0] = p0; x2p[row1] = p1; }

    // per-k mixture weights for this lane's 32 k's -> registers
    float wreg[32];
    {
        const float* wrow = wbuf + (size_t)b * Kc + ln;
        #pragma unroll
        for (int kt = 0; kt < 32; ++kt) wreg[kt] = wrow[kt * 16];
    }
    __syncthreads();

    const f32x4 zero = {0.f, 0.f, 0.f, 0.f};
    float acc0[4] = {0.f, 0.f, 0.f, 0.f};
    float acc1[4] = {0.f, 0.f, 0.f, 0.f};

    #pragma unroll
    for (int kt = 0; kt < 32; ++kt) {
        const bf16x8 bfr = *(const bf16x8*)&mlds[(kt * 16 + ln) * 32 + q * 8];
        f32x4 d0 = __builtin_amdgcn_mfma_f32_16x16x32_bf16(a0, bfr, zero, 0, 0, 0);
        f32x4 d1 = __builtin_amdgcn_mfma_f32_16x16x32_bf16(a1, bfr, zero, 0, 0, 0);
        #pragma unroll
        for (int r = 0; r < 4; ++r) {
            acc0[r] = fmaf(wreg[kt], EXP2F(d0[r]), acc0[r]);
            acc1[r] = fmaf(wreg[kt], EXP2F(d1[r]), acc1[r]);
        }
    }

    // reduce over the 16 k-columns (low-4 lane bits), then write
    #pragma unroll
    for (int r = 0; r < 4; ++r) {
        float s0v = acc0[r], s1v = acc1[r];
        s0v += __shfl_xor(s0v, 1); s0v += __shfl_xor(s0v, 2);
        s0v += __shfl_xor(s0v, 4); s0v += __shfl_xor(s0v, 8);
        s1v += __shfl_xor(s1v, 1); s1v += __shfl_xor(s1v, 2);
        s1v += __shfl_xor(s1v, 4); s1v += __shfl_xor(s1v, 8);
        if (ln == 0) {
            const int r0 = rw + q * 4 + r;       // C/D row = quad*4 + reg
            const int r1 = r0 + 16;
            out[(size_t)b * Sc + s0 + r0] = 0.5f * x2p[r0] + LOG_NORM - LN2 * LOG2F(s0v);
            out[(size_t)b * Sc + s0 + r1] = 0.5f * x2p[r1] + LOG_NORM - LN2 * LOG2F(s1v);
        }
    }
}

extern "C" void kernel_launch(void* const* d_in, const int* in_sizes, int n_in,
                              void* d_out, int out_size, void* d_ws, size_t ws_size,
                              hipStream_t stream) {
    const float* x      = (const float*)d_in[0];
    const float* logits = (const float*)d_in[1];
    const float* means  = (const float*)d_in[2];
    float* out = (float*)d_out;
    (void)in_sizes; (void)n_in; (void)out_size; (void)ws_size;

    unsigned short* mbf  = (unsigned short*)d_ws;              // 32 KB
    float*          wbuf = (float*)((char*)d_ws + 32768);      // 512 KB

    hipLaunchKernelGGL(gm_prep, dim3(Bc), dim3(256), 0, stream,
                       logits, means, wbuf, mbf);
    hipLaunchKernelGGL(gm_main, dim3(Bc * (Sc / ST)), dim3(256), 0, stream,
                       x, wbuf, mbf, out);
}

// Round 4
// 95.265 us; speedup vs baseline: 1.2889x; 1.2889x over previous
//
#include <hip/hip_runtime.h>
#include <math.h>

// Problem constants (fixed by setup_inputs)
constexpr int Bc = 256, Sc = 1024, Dc = 32, Kc = 512;
constexpr int ST = 128;                      // s-rows per main block
constexpr float LOG2E    = 1.4426950408889634f;
constexpr float LN2      = 0.6931471805599453f;
constexpr float LOG_NORM = 29.40603306051f;  // D * 0.5 * log(2*pi)

typedef __attribute__((ext_vector_type(8))) short          bf16x8;
typedef __attribute__((ext_vector_type(8))) unsigned short u16x8;
typedef __attribute__((ext_vector_type(4))) float          f32x4;

#if __has_builtin(__builtin_amdgcn_exp2f)
#define EXP2F(v) __builtin_amdgcn_exp2f(v)
#else
#define EXP2F(v) exp2f(v)
#endif
#if __has_builtin(__builtin_amdgcn_logf)
#define LOG2F(v) __builtin_amdgcn_logf(v)
#else
#define LOG2F(v) log2f(v)
#endif

__device__ __forceinline__ unsigned short f2bf(float f) {
    unsigned u = __float_as_uint(f);
    u += 0x7fff + ((u >> 16) & 1);           // round-to-nearest-even
    return (unsigned short)(u >> 16);
}

// XOR-swizzled LDS offset (ushort units): row stride 32 bf16 (64B),
// chunk = 16B octet 0..3, XORed with (row>>1)&3. Measured 0 conflicts (R2).
__device__ __forceinline__ int swz(int row, int chunk) {
    return row * 32 + ((chunk ^ ((row >> 1) & 3)) << 3);
}

// ---------------- pre-kernel: per-(b,k) weights + means->bf16 ----------------
__global__ __launch_bounds__(256)
void gm_prep(const float* __restrict__ logits, const float* __restrict__ means,
             float* __restrict__ wbuf, unsigned short* __restrict__ mbf)
{
    __shared__ float red[8];
    const int tid  = threadIdx.x;
    const int lane = tid & 63;
    const int wid  = tid >> 6;
    const int b    = blockIdx.x;

    const float l0 = logits[b * Kc + tid];
    const float l1 = logits[b * Kc + tid + 256];
    float mx = fmaxf(l0, l1);
    #pragma unroll
    for (int off = 32; off >= 1; off >>= 1) mx = fmaxf(mx, __shfl_xor(mx, off));
    if (lane == 0) red[wid] = mx;
    __syncthreads();
    mx = fmaxf(fmaxf(red[0], red[1]), fmaxf(red[2], red[3]));
    float sm = EXP2F((l0 - mx) * LOG2E) + EXP2F((l1 - mx) * LOG2E);
    #pragma unroll
    for (int off = 32; off >= 1; off >>= 1) sm += __shfl_xor(sm, off);
    if (lane == 0) red[4 + wid] = sm;
    __syncthreads();
    sm = red[4] + red[5] + red[6] + red[7];
    const float lse = mx + LN2 * LOG2F(sm);

    #pragma unroll
    for (int rr = 0; rr < 2; ++rr) {
        const int k = tid + rr * 256;
        const float4* mp = (const float4*)(means + (size_t)k * Dc);
        float m2 = 0.f;
        #pragma unroll
        for (int i = 0; i < 8; ++i) {
            float4 v = mp[i];
            m2 += v.x*v.x + v.y*v.y + v.z*v.z + v.w*v.w;
        }
        const float lg = (rr == 0) ? l0 : l1;
        wbuf[(size_t)b * Kc + k] = EXP2F((lg - lse - 0.5f * m2) * LOG2E);
    }

    // means -> bf16 (block b converts rows 2b, 2b+1)
    if (tid < 64) {
        const int row = 2 * b + (tid >> 5);
        const int col = tid & 31;
        mbf[row * 32 + col] = f2bf(means[(size_t)row * 32 + col]);
    }
}

// ---------------- main kernel ----------------
// grid(Bc * Sc/ST), block(256) = 4 waves; wave owns 32 s-rows.
__global__ __launch_bounds__(256)
void gm_main(const float* __restrict__ x, const float* __restrict__ wbuf,
             const unsigned short* __restrict__ mbf, float* __restrict__ out)
{
    __shared__ unsigned short mlds[Kc * 32];  // 32 KB bf16 means, XOR-swizzled
    __shared__ float wlds[Kc];                //  2 KB mixture weights
    __shared__ float x2p[ST];                 // per-row sum(x^2)

    const int tid  = threadIdx.x;
    const int lane = tid & 63;
    const int wid  = tid >> 6;
    const int b    = blockIdx.x >> 3;
    const int s0   = (blockIdx.x & 7) * ST;
    const int q    = lane >> 4;               // k-octet of contraction dim
    const int ln   = lane & 15;
    const int rw   = wid * 32;

    // stage means (32 KB vector copy into swizzled layout) + weights
    {
        const u16x8* src = (const u16x8*)mbf;
        #pragma unroll
        for (int j = 0; j < 8; ++j) {
            const int c = tid + j * 256;       // 16B-chunk index 0..2047
            *(u16x8*)&mlds[swz(c >> 2, c & 3)] = src[c];
        }
        wlds[tid]       = wbuf[(size_t)b * Kc + tid];
        wlds[tid + 256] = wbuf[(size_t)b * Kc + tid + 256];
    }

    // x A-fragments direct from global (row fully consumed by the 4 q-lanes)
    const int row0 = rw + ln, row1 = row0 + 16;
    const float4* xp0 = (const float4*)(x + ((size_t)b * Sc + s0 + row0) * Dc) + q * 2;
    const float4* xp1 = (const float4*)(x + ((size_t)b * Sc + s0 + row1) * Dc) + q * 2;
    float4 v0 = xp0[0], v1 = xp0[1];
    float4 u0 = xp1[0], u1 = xp1[1];

    bf16x8 a0, a1;
    a0[0]=(short)f2bf(v0.x*LOG2E); a0[1]=(short)f2bf(v0.y*LOG2E);
    a0[2]=(short)f2bf(v0.z*LOG2E); a0[3]=(short)f2bf(v0.w*LOG2E);
    a0[4]=(short)f2bf(v1.x*LOG2E); a0[5]=(short)f2bf(v1.y*LOG2E);
    a0[6]=(short)f2bf(v1.z*LOG2E); a0[7]=(short)f2bf(v1.w*LOG2E);
    a1[0]=(short)f2bf(u0.x*LOG2E); a1[1]=(short)f2bf(u0.y*LOG2E);
    a1[2]=(short)f2bf(u0.z*LOG2E); a1[3]=(short)f2bf(u0.w*LOG2E);
    a1[4]=(short)f2bf(u1.x*LOG2E); a1[5]=(short)f2bf(u1.y*LOG2E);
    a1[6]=(short)f2bf(u1.z*LOG2E); a1[7]=(short)f2bf(u1.w*LOG2E);

    float p0 = v0.x*v0.x + v0.y*v0.y + v0.z*v0.z + v0.w*v0.w
             + v1.x*v1.x + v1.y*v1.y + v1.z*v1.z + v1.w*v1.w;
    float p1 = u0.x*u0.x + u0.y*u0.y + u0.z*u0.z + u0.w*u0.w
             + u1.x*u1.x + u1.y*u1.y + u1.z*u1.z + u1.w*u1.w;
    p0 += __shfl_xor(p0, 16); p0 += __shfl_xor(p0, 32);
    p1 += __shfl_xor(p1, 16); p1 += __shfl_xor(p1, 32);
    if (q == 0) { x2p[row0] = p0; x2p[row1] = p1; }
    __syncthreads();

    const f32x4 zero = {0.f, 0.f, 0.f, 0.f};
    float acc0[4] = {0.f, 0.f, 0.f, 0.f};
    float acc1[4] = {0.f, 0.f, 0.f, 0.f};

    #pragma unroll 8
    for (int kt = 0; kt < 32; ++kt) {
        const int krow = kt * 16 + ln;
        const bf16x8 bfr = *(const bf16x8*)&mlds[swz(krow, q)];
        const float  wv  = wlds[krow];        // 16 consecutive floats, bcast over q
        f32x4 d0 = __builtin_amdgcn_mfma_f32_16x16x32_bf16(a0, bfr, zero, 0, 0, 0);
        f32x4 d1 = __builtin_amdgcn_mfma_f32_16x16x32_bf16(a1, bfr, zero, 0, 0, 0);
        #pragma unroll
        for (int r = 0; r < 4; ++r) {
            acc0[r] = fmaf(wv, EXP2F(d0[r]), acc0[r]);
            acc1[r] = fmaf(wv, EXP2F(d1[r]), acc1[r]);
        }
    }

    // reduce over the 16 k-columns (low-4 lane bits), then write
    #pragma unroll
    for (int r = 0; r < 4; ++r) {
        float s0v = acc0[r], s1v = acc1[r];
        s0v += __shfl_xor(s0v, 1); s0v += __shfl_xor(s0v, 2);
        s0v += __shfl_xor(s0v, 4); s0v += __shfl_xor(s0v, 8);
        s1v += __shfl_xor(s1v, 1); s1v += __shfl_xor(s1v, 2);
        s1v += __shfl_xor(s1v, 4); s1v += __shfl_xor(s1v, 8);
        if (ln == 0) {
            const int r0 = rw + q * 4 + r;       // C/D row = quad*4 + reg
            const int r1 = r0 + 16;
            out[(size_t)b * Sc + s0 + r0] = 0.5f * x2p[r0] + LOG_NORM - LN2 * LOG2F(s0v);
            out[(size_t)b * Sc + s0 + r1] = 0.5f * x2p[r1] + LOG_NORM - LN2 * LOG2F(s1v);
        }
    }
}

extern "C" void kernel_launch(void* const* d_in, const int* in_sizes, int n_in,
                              void* d_out, int out_size, void* d_ws, size_t ws_size,
                              hipStream_t stream) {
    const float* x      = (const float*)d_in[0];
    const float* logits = (const float*)d_in[1];
    const float* means  = (const float*)d_in[2];
    float* out = (float*)d_out;
    (void)in_sizes; (void)n_in; (void)out_size; (void)ws_size;

    unsigned short* mbf  = (unsigned short*)d_ws;              // 32 KB
    float*          wbuf = (float*)((char*)d_ws + 32768);      // 512 KB

    hipLaunchKernelGGL(gm_prep, dim3(Bc), dim3(256), 0, stream,
                       logits, means, wbuf, mbf);
    hipLaunchKernelGGL(gm_main, dim3(Bc * (Sc / ST)), dim3(256), 0, stream,
                       x, wbuf, mbf, out);
}